// Round 1
// baseline (272.068 us; speedup 1.0000x reference)
//
#include <hip/hip_runtime.h>
#include <hip/hip_bf16.h>

// Problem constants (fixed by reference)
#define N_PER    4096
#define KNBR     16
#define NTOT     32768
#define D_IN     32
#define D_H      64
#define D_OUT    128
#define E_TOT    (NTOT * KNBR)            // 524288

#define OUT1_OFF (NTOT * D_OUT)           // pos output offset (elements)
#define OUT2_OFF (NTOT * D_OUT + NTOT*3)  // batch output offset (elements)

#define KNN_INF    3.4e38f
#define KNN_MARGIN 4e-3f   // covers |d'_mfma - d_exact| (<~9e-4 worst case) x2

typedef __attribute__((ext_vector_type(8)))  short bf16x8;   // MFMA A/B frag
typedef __attribute__((ext_vector_type(4)))  float f32x4;    // MFMA C/D frag (16x16)
typedef __attribute__((ext_vector_type(16))) float f32x16;   // MFMA C/D frag (32x32)

// ---------------------------------------------------------------------------
// Static device scratch; every buffer fully (re)written each call.
// ---------------------------------------------------------------------------
__device__ float          g_posf[NTOT * 3];       // f32 pos (exact bf16 upconvert)
__device__ float          g_scf[NTOT];            // per-node |p|^2 (unfused, = numpy sq)
__device__ __attribute__((aligned(16))) unsigned short g_knnA[NTOT * 16]; // per-node MFMA A frag (query side)
__device__ __attribute__((aligned(16))) unsigned short g_knnB[NTOT * 16]; // per-node MFMA B frag (candidate side)
__device__ int            g_nbr[E_TOT];
__device__ unsigned short g_base1h[NTOT * D_H];   // bf16 base1
__device__ uint4          g_Bfrag[2 * 4 * 64];    // W2 B-fragments [ks][nt][lane]
__device__ float          g_Wd[3 * D_H];
__device__ float          g_fb2v[D_H];
__device__ int            g_cnt[NTOT];
__device__ int            g_bsum[NTOT / 256];     // per-block cnt sums (scan)
__device__ int            g_offs[NTOT + 1];
__device__ int            g_cursor[NTOT];
__device__ int            g_inlist[E_TOT];
__device__ float          g_agg[NTOT * D_H];      // zero-inited (atomicMax targets)

__device__ __forceinline__ float ldf(const void* p, int i, int bf) {
    if (bf) return __uint_as_float(((unsigned)((const unsigned short*)p)[i]) << 16);
    return ((const float*)p)[i];
}
__device__ __forceinline__ unsigned bf16rne(float f) {
    unsigned u = __float_as_uint(f);
    return (u + 0x7FFFu + ((u >> 16) & 1u)) >> 16;
}
__device__ __forceinline__ void stf(void* p, int i, float v, int bf) {
    if (bf) ((unsigned short*)p)[i] = (unsigned short)bf16rne(v);
    else    ((float*)p)[i] = v;
}
__device__ __forceinline__ float b2f(unsigned short h) {
    return __uint_as_float(((unsigned)h) << 16);
}
// Inline dtype probe: majority vote over 64 words of a float tensor.
__device__ __forceinline__ int wave_probe(const void* x) {
    unsigned wv = ((const unsigned*)x)[threadIdx.x & 63];
    unsigned e = (wv >> 7) & 0xFFu;
    unsigned long long mk = __ballot(e >= 110u && e <= 140u);
    return (__popcll(mk) >= 32) ? 1 : 0;
}

// ---------------------------------------------------------------------------
// prep: blocks 0..1023    = pos->f32, |p|^2, knn MFMA frags, zero cnt/agg
//       blocks 1024..2047 = base1[n][d] (vectorized dual-dtype x loads)
//       block  2048       = stage edge-kernel weights (Wd, fb2, W2 B-frags)
// ---------------------------------------------------------------------------
__global__ __launch_bounds__(256) void prep_kernel(const void* __restrict__ x,
                                                   const void* __restrict__ pos,
                                                   const void* __restrict__ fW1,
                                                   const void* __restrict__ fb1,
                                                   const void* __restrict__ fW2,
                                                   const void* __restrict__ fb2) {
    const int bf = wave_probe(x);
    const int b = blockIdx.x;
    if (b < 1024) {
        const int i0 = b * 256 + threadIdx.x;
        const int stride = 1024 * 256;
        for (int i = i0; i < NTOT * 3; i += stride) g_posf[i] = ldf(pos, i, bf);
        {
#pragma clang fp contract(off)
            for (int i = i0; i < NTOT; i += stride) {
                float a  = ldf(pos, i * 3 + 0, bf);
                float c2 = ldf(pos, i * 3 + 1, bf);
                float c3 = ldf(pos, i * 3 + 2, bf);
                float sc = a * a + c2 * c2 + c3 * c3;
                g_scf[i] = sc;
                g_cnt[i] = 0;
                // hi/lo bf16 split of coords and |p|^2 for the MFMA distance scan.
                // K layout (16 slots, 11 used):
                //   A = [-2hx,-2hy,-2hz, -2lx,-2ly,-2lz, -2hx,-2hy,-2hz, 1, 1, 0..]
                //   B = [ hx,  hy,  hz,   hx,  hy,  hz,   lx,  ly,  lz, sch,scl,0..]
                // sum(A*B) = sc' - 2(h.h' + l.h' + h.l')  ~= sc' - 2 p.p'
                unsigned hx = bf16rne(a),  hy = bf16rne(c2), hz = bf16rne(c3);
                float fhx = b2f(hx), fhy = b2f(hy), fhz = b2f(hz);
                unsigned lx = bf16rne(a - fhx), ly = bf16rne(c2 - fhy), lz = bf16rne(c3 - fhz);
                unsigned sch = bf16rne(sc);
                unsigned scl = bf16rne(sc - b2f(sch));
                unsigned nx = bf16rne(-2.0f * fhx), ny = bf16rne(-2.0f * fhy), nz = bf16rne(-2.0f * fhz);
                unsigned ox = bf16rne(-2.0f * b2f(lx)), oy = bf16rne(-2.0f * b2f(ly)), oz = bf16rne(-2.0f * b2f(lz));
                const unsigned ONEB = 0x3F80u;
                uint4 A0 = make_uint4(nx | (ny << 16), nz | (ox << 16), oy | (oz << 16), nx | (ny << 16));
                uint4 A1 = make_uint4(nz | (ONEB << 16), ONEB, 0u, 0u);
                uint4 B0 = make_uint4(hx | (hy << 16), hz | (hx << 16), hy | (hz << 16), lx | (ly << 16));
                uint4 B1 = make_uint4(lz | (sch << 16), scl, 0u, 0u);
                *(uint4*)&g_knnA[(size_t)i * 16]     = A0;
                *(uint4*)&g_knnA[(size_t)i * 16 + 8] = A1;
                *(uint4*)&g_knnB[(size_t)i * 16]     = B0;
                *(uint4*)&g_knnB[(size_t)i * 16 + 8] = B1;
            }
        }
        for (int i = i0; i < NTOT * D_H; i += stride) g_agg[i] = 0.0f;
    } else if (b < 2048) {
        int lane = threadIdx.x & 63, wid = threadIdx.x >> 6;
        int n0 = (b - 1024) * 32 + wid * 8;
        float wcol[D_IN];
#pragma unroll
        for (int k = 0; k < D_IN; k++) wcol[k] = ldf(fW1, k * D_H + lane, bf);
        float bb = ldf(fb1, lane, bf);
        if (bf) {
            const unsigned short* xp = (const unsigned short*)x;
            for (int r = 0; r < 8; r++) {
                int n = n0 + r;
                const uint4* xr = (const uint4*)(xp + (size_t)n * D_IN);  // 32 bf16 = 4x uint4
                float acc = bb;
#pragma unroll
                for (int q4 = 0; q4 < 4; q4++) {
                    uint4 w4 = xr[q4];
                    unsigned ww[4] = {w4.x, w4.y, w4.z, w4.w};
#pragma unroll
                    for (int p = 0; p < 4; p++) {
                        int k = q4 * 8 + p * 2;
                        acc += __uint_as_float(ww[p] << 16) * wcol[k];
                        acc += __uint_as_float(ww[p] & 0xFFFF0000u) * wcol[k + 1];
                    }
                }
                g_base1h[(size_t)n * D_H + lane] = (unsigned short)bf16rne(acc);
            }
        } else {
            const float* xp = (const float*)x;
            for (int r = 0; r < 8; r++) {
                int n = n0 + r;
                const float4* xr = (const float4*)(xp + (size_t)n * D_IN);
                float acc = bb;
#pragma unroll
                for (int q4 = 0; q4 < 8; q4++) {
                    float4 w4 = xr[q4];
                    int k = q4 * 4;
                    acc += w4.x * wcol[k] + w4.y * wcol[k + 1] + w4.z * wcol[k + 2] + w4.w * wcol[k + 3];
                }
                g_base1h[(size_t)n * D_H + lane] = (unsigned short)bf16rne(acc);
            }
        }
    } else {
        for (int t = threadIdx.x; t < 3 * D_H; t += 256) g_Wd[t] = ldf(fW1, D_IN * D_H + t, bf);
        if (threadIdx.x < D_H) g_fb2v[threadIdx.x] = ldf(fb2, threadIdx.x, bf);
        for (int idx = threadIdx.x; idx < 512; idx += 256) {
            int lane = idx & 63, nt = (idx >> 6) & 3, ks = idx >> 8;
            int n = nt * 16 + (lane & 15);
            int k0 = ks * 32 + ((lane >> 4) << 3);
            unsigned wds[4];
#pragma unroll
            for (int jp = 0; jp < 4; jp++) {
                unsigned lo = bf16rne(ldf(fW2, (k0 + 2 * jp) * D_H + n, bf));
                unsigned hi = bf16rne(ldf(fW2, (k0 + 2 * jp + 1) * D_H + n, bf));
                wds[jp] = lo | (hi << 16);
            }
            g_Bfrag[idx] = make_uint4(wds[0], wds[1], wds[2], wds[3]);
        }
    }
}

// ---------------------------------------------------------------------------
// 64-lane bitonic helpers (identical networks to the previously-passing kernel)
// ---------------------------------------------------------------------------
__device__ __forceinline__ void knn_sortval(float& v, int lane) {
#pragma unroll
    for (int k = 2; k <= 64; k <<= 1) {
#pragma unroll
        for (int j2 = k >> 1; j2 >= 1; j2 >>= 1) {
            float pv = __shfl_xor(v, j2);
            bool keepMin = (((lane & j2) == 0) == ((lane & k) == 0));
            bool tp = ((pv < v) == keepMin);
            v = tp ? pv : v;
        }
    }
}
__device__ __forceinline__ void knn_sortpair(float& d, int& idx, int lane) {
#pragma unroll
    for (int k = 2; k <= 64; k <<= 1) {
#pragma unroll
        for (int j2 = k >> 1; j2 >= 1; j2 >>= 1) {
            float pd = __shfl_xor(d, j2);
            int   pi = __shfl_xor(idx, j2);
            bool keepMin = (((lane & j2) == 0) == ((lane & k) == 0));
            bool lt = (pd < d) || (pd == d && pi < idx);
            bool tp = (lt == keepMin);
            d   = tp ? pd : d;
            idx = tp ? pi : idx;
        }
    }
}

// ---------------------------------------------------------------------------
// KNN via MFMA distance tiles. 512 threads = 8 waves per block, 64 queries.
// wave w: M-tile = (w&1)*32 queries, candidate quarter = (w>>1)*1024.
// d' = sc_j - 2 p_i.p_j computed by v_mfma_f32_32x32x16_bf16 on hi/lo-split
// frags (error <~9e-4, covered by KNN_MARGIN).
// scan1: per-(row, col, quarter) mins -> LDS -> T'[q] = 16th-smallest of 64
//        disjoint union-mins + margin (guarantees >=16 survivors).
// scan2: identical MFMA recompute, ballot-compact survivors per query.
// final: exact unfused f32 d + (d, idx) bitonic top-16 (bit-identical to the
//        previous kernel); exact slow path if > 64 survivors.
// ---------------------------------------------------------------------------
__global__ __launch_bounds__(512) void knn_kernel() {
#pragma clang fp contract(off)
    __shared__ float          s_min[64][128];
    __shared__ float          s_T[64];
    __shared__ int            s_cnt[64];
    __shared__ unsigned short s_list[64][64];

    const int t       = threadIdx.x;
    const int lane    = t & 63;
    const int w       = t >> 6;
    const int mtile   = w & 1;
    const int quarter = w >> 1;
    const int half    = lane >> 5;
    const int col     = lane & 31;
    const int qbase   = blockIdx.x * 64;
    const int cbase   = (qbase >> 12) << 12;

    if (t < 64) s_cnt[t] = 0;

    // A-frag for this lane's query row (row = lane&31, k-half = lane>>5)
    const int qrow = qbase + mtile * 32 + col;
    const bf16x8 afrag = *(const bf16x8*)&g_knnA[(size_t)qrow * 16 + half * 8];
    // B-frag base for this lane's candidate column; +512 ushorts per 32-cand tile
    const unsigned short* bp = g_knnB + (size_t)(cbase + quarter * 1024 + col) * 16 + half * 8;

    const f32x16 z = {};

    // ---- scan 1: min d' per (query row, col-class, quarter) ----
    float m[16];
#pragma unroll
    for (int i = 0; i < 16; i++) m[i] = KNN_INF;
    {
        bf16x8 nb0 = *(const bf16x8*)(bp + 0 * 512);
        bf16x8 nb1 = *(const bf16x8*)(bp + 1 * 512);
        bf16x8 nb2 = *(const bf16x8*)(bp + 2 * 512);
        bf16x8 nb3 = *(const bf16x8*)(bp + 3 * 512);
        for (int g = 0; g < 8; g++) {
            bf16x8 cb0 = nb0, cb1 = nb1, cb2 = nb2, cb3 = nb3;
            if (g < 7) {
                const unsigned short* np = bp + (g + 1) * 2048;
                nb0 = *(const bf16x8*)(np + 0 * 512);
                nb1 = *(const bf16x8*)(np + 1 * 512);
                nb2 = *(const bf16x8*)(np + 2 * 512);
                nb3 = *(const bf16x8*)(np + 3 * 512);
            }
            f32x16 c0 = __builtin_amdgcn_mfma_f32_32x32x16_bf16(afrag, cb0, z, 0, 0, 0);
            f32x16 c1 = __builtin_amdgcn_mfma_f32_32x32x16_bf16(afrag, cb1, z, 0, 0, 0);
            f32x16 c2 = __builtin_amdgcn_mfma_f32_32x32x16_bf16(afrag, cb2, z, 0, 0, 0);
            f32x16 c3 = __builtin_amdgcn_mfma_f32_32x32x16_bf16(afrag, cb3, z, 0, 0, 0);
#pragma unroll
            for (int i = 0; i < 16; i++)
                m[i] = fminf(m[i], fminf(fminf(c0[i], c1[i]), fminf(c2[i], c3[i])));
        }
    }
    // C layout (32x32): col = lane&31, row = (reg&3) + 8*(reg>>2) + 4*(lane>>5)
#pragma unroll
    for (int i = 0; i < 16; i++) {
        int row = (i & 3) + 8 * (i >> 2) + 4 * half;
        s_min[mtile * 32 + row][quarter * 32 + col] = m[i];
    }
    __syncthreads();

    // ---- threshold: T'[q] = 16th smallest of 64 disjoint union-mins + margin ----
    for (int it = 0; it < 8; it++) {
        int q = w * 8 + it;
        float v = fminf(s_min[q][lane], s_min[q][64 + lane]);
        knn_sortval(v, lane);
        if (lane == 15) s_T[q] = v + KNN_MARGIN;
    }
    __syncthreads();

    // ---- scan 2: identical MFMA recompute, compact survivors ----
    float Treg[16];
#pragma unroll
    for (int i = 0; i < 16; i++) {
        int row = (i & 3) + 8 * (i >> 2) + 4 * half;
        Treg[i] = s_T[mtile * 32 + row];
    }
    {
        bf16x8 nb0 = *(const bf16x8*)(bp + 0 * 512);
        bf16x8 nb1 = *(const bf16x8*)(bp + 1 * 512);
        bf16x8 nb2 = *(const bf16x8*)(bp + 2 * 512);
        bf16x8 nb3 = *(const bf16x8*)(bp + 3 * 512);
        for (int g = 0; g < 8; g++) {
            bf16x8 cb[4] = {nb0, nb1, nb2, nb3};
            if (g < 7) {
                const unsigned short* np = bp + (g + 1) * 2048;
                nb0 = *(const bf16x8*)(np + 0 * 512);
                nb1 = *(const bf16x8*)(np + 1 * 512);
                nb2 = *(const bf16x8*)(np + 2 * 512);
                nb3 = *(const bf16x8*)(np + 3 * 512);
            }
#pragma unroll
            for (int u = 0; u < 4; u++) {
                f32x16 c = __builtin_amdgcn_mfma_f32_32x32x16_bf16(afrag, cb[u], z, 0, 0, 0);
                int lc = quarter * 1024 + (g * 4 + u) * 32 + col;
#pragma unroll
                for (int i = 0; i < 16; i++) {
                    bool p = (c[i] <= Treg[i]);
                    unsigned long long mk = __ballot(p);
                    if (mk) {
                        int q = mtile * 32 + (i & 3) + 8 * (i >> 2) + 4 * half;
                        unsigned mk32 = (unsigned)(mk >> (half * 32));
                        int base = 0;
                        if (col == 0) base = atomicAdd(&s_cnt[q], __popc(mk32));
                        base = __shfl(base, half * 32);
                        if (p) {
                            int slot = base + __popc(mk32 & ((1u << col) - 1u));
                            if (slot < 64) s_list[q][slot] = (unsigned short)lc;
                        }
                    }
                }
            }
        }
    }
    __syncthreads();

    // ---- final: exact unfused d for survivors, (d, idx) bitonic top-16 ----
    for (int it = 0; it < 8; it++) {
        int ql = w * 8 + it;
        int q  = qbase + ql;
        float qx = g_posf[q * 3 + 0], qy = g_posf[q * 3 + 1], qz = g_posf[q * 3 + 2];
        float qs = g_scf[q];
        int S = s_cnt[ql];
        if (S <= 64) {
            int idx = 0x7FFFFFFF;
            float d = KNN_INF;
            if (lane < S) {
                idx = cbase + (int)s_list[ql][lane];
                float px = g_posf[idx * 3], py = g_posf[idx * 3 + 1], pz = g_posf[idx * 3 + 2];
                float sc = g_scf[idx];
                float dot = px * qx + py * qy + pz * qz;
                d = (qs + sc) - 2.0f * dot;
            }
            knn_sortpair(d, idx, lane);
            if (lane < 16) {
                g_nbr[q * KNBR + lane] = idx;
                atomicAdd(&g_cnt[idx & (NTOT - 1)], 1);
            }
        } else {
            // exact slow path: 16 sequential argmin passes over graph's pos
            const float* cp  = g_posf + cbase * 3;
            const float* csc = g_scf + cbase;
            float lastd = -KNN_INF; int lasti = -1;
            for (int t16 = 0; t16 < 16; t16++) {
                float bd = KNN_INF; int bi = 0x7FFFFFFF;
                for (int cc = 0; cc < 64; cc++) {
                    int jj = cc * 64 + lane;
                    float px = cp[jj * 3], py = cp[jj * 3 + 1], pz = cp[jj * 3 + 2];
                    float sc = csc[jj];
                    float dot = px * qx + py * qy + pz * qz;
                    float dd = (qs + sc) - 2.0f * dot;
                    int gj = cbase + jj;
                    bool after  = (dd > lastd) || (dd == lastd && gj > lasti);
                    bool better = (dd < bd) || (dd == bd && gj < bi);
                    if (after && better) { bd = dd; bi = gj; }
                }
#pragma unroll
                for (int s2 = 1; s2 < 64; s2 <<= 1) {
                    float od = __shfl_xor(bd, s2);
                    int   oi = __shfl_xor(bi, s2);
                    if (od < bd || (od == bd && oi < bi)) { bd = od; bi = oi; }
                }
                if (lane == 0) {
                    g_nbr[q * KNBR + t16] = bi;
                    atomicAdd(&g_cnt[bi & (NTOT - 1)], 1);
                }
                lastd = bd; lasti = bi;
            }
        }
    }
}

// ---------------------------------------------------------------------------
// scanA: per-256-block sums of g_cnt
// ---------------------------------------------------------------------------
__global__ __launch_bounds__(256) void scanA_kernel() {
    __shared__ int red[4];
    int t = threadIdx.x, lane = t & 63, w = t >> 6;
    int v = g_cnt[blockIdx.x * 256 + t];
    int s = v;
#pragma unroll
    for (int off = 1; off < 64; off <<= 1) s += __shfl_xor(s, off);
    if (lane == 0) red[w] = s;
    __syncthreads();
    if (t == 0) g_bsum[blockIdx.x] = red[0] + red[1] + red[2] + red[3];
}

// ---------------------------------------------------------------------------
// scanC: each block redundantly sums its prior block-sums, then local scan.
// ---------------------------------------------------------------------------
__global__ __launch_bounds__(256) void scanC_kernel() {
    __shared__ int sred[4];
    __shared__ int wsum[4];
    int t = threadIdx.x, lane = t & 63, w = t >> 6;
    int contrib = (t < 128 && t < blockIdx.x) ? g_bsum[t] : 0;
    int rs = contrib;
#pragma unroll
    for (int off = 1; off < 64; off <<= 1) rs += __shfl_xor(rs, off);
    if (lane == 0) sred[w] = rs;
    __syncthreads();
    int base = sred[0] + sred[1] + sred[2] + sred[3];

    int i = blockIdx.x * 256 + t;
    int v = g_cnt[i];
    int inc = v;
#pragma unroll
    for (int off = 1; off < 64; off <<= 1) {
        int u = __shfl_up(inc, off);
        if (lane >= off) inc += u;
    }
    if (lane == 63) wsum[w] = inc;
    __syncthreads();
    int wbase = 0;
    for (int k = 0; k < w; k++) wbase += wsum[k];
    int excl = base + wbase + inc - v;
    g_offs[i] = excl;
    g_cursor[i] = excl;
    if (i == NTOT - 1) g_offs[NTOT] = E_TOT;
}

__global__ void scatter_kernel() {
    int e = blockIdx.x * 256 + threadIdx.x;
    int c = g_nbr[e] & (NTOT - 1);
    int slot = atomicAdd(&g_cursor[c], 1);
    g_inlist[slot & (E_TOT - 1)] = e;
}

// ---------------------------------------------------------------------------
// Edge kernel (MFMA): unchanged.
// ---------------------------------------------------------------------------
__global__ __launch_bounds__(256) void edge_kernel() {
    __shared__ unsigned short sA[256 * 72];
    __shared__ int scol[256];
    const int t    = threadIdx.x;
    const int lane = t & 63;
    const int w    = t >> 6;
    const int slot0 = blockIdx.x * 256;

    // ---- phase 1: h1 for this thread's edge ----
    {
        int e = g_inlist[slot0 + t];
        int n = (e >> 4) & (NTOT - 1);
        int j = g_nbr[e] & (NTOT - 1);
        scol[t] = j;
        float dx = g_posf[n * 3 + 0] - g_posf[j * 3 + 0];
        float dy = g_posf[n * 3 + 1] - g_posf[j * 3 + 1];
        float dz = g_posf[n * 3 + 2] - g_posf[j * 3 + 2];
        const unsigned short* b1 = g_base1h + (size_t)n * D_H;
#pragma unroll
        for (int d0 = 0; d0 < D_H; d0 += 8) {
            uint4 p = *(const uint4*)(b1 + d0);
            unsigned pw[4] = {p.x, p.y, p.z, p.w};
            unsigned qw[4];
#pragma unroll
            for (int jp = 0; jp < 4; jp++) {
                int d = d0 + 2 * jp;
                float v0 = __uint_as_float(pw[jp] << 16)
                         + dx * g_Wd[d]     + dy * g_Wd[64 + d]     + dz * g_Wd[128 + d];
                float v1 = __uint_as_float(pw[jp] & 0xFFFF0000u)
                         + dx * g_Wd[d + 1] + dy * g_Wd[64 + d + 1] + dz * g_Wd[128 + d + 1];
                v0 = fmaxf(v0, 0.f); v1 = fmaxf(v1, 0.f);
                qw[jp] = bf16rne(v0) | (bf16rne(v1) << 16);
            }
            *(uint4*)(&sA[t * 72 + d0]) = make_uint4(qw[0], qw[1], qw[2], qw[3]);
        }
    }
    __syncthreads();

    // ---- phase 2: MFMA h2 = h1 @ W2 ----
    f32x4 acc[4][4];
#pragma unroll
    for (int a = 0; a < 4; a++)
#pragma unroll
        for (int b = 0; b < 4; b++) acc[a][b] = (f32x4){0.f, 0.f, 0.f, 0.f};

    const int quad = lane >> 4;
    const int l15  = lane & 15;
#pragma unroll
    for (int ks = 0; ks < 2; ks++) {
        bf16x8 bfrag[4];
#pragma unroll
        for (int nt = 0; nt < 4; nt++)
            bfrag[nt] = ((const bf16x8*)g_Bfrag)[ks * 256 + nt * 64 + lane];
#pragma unroll
        for (int mt = 0; mt < 4; mt++) {
            int row = w * 64 + mt * 16 + l15;
            bf16x8 afrag = *(const bf16x8*)(&sA[row * 72 + ks * 32 + quad * 8]);
#pragma unroll
            for (int nt = 0; nt < 4; nt++)
                acc[mt][nt] = __builtin_amdgcn_mfma_f32_16x16x32_bf16(afrag, bfrag[nt], acc[mt][nt], 0, 0, 0);
        }
    }
    __syncthreads();

    // ---- phase 3a: relu(h2 + b2) -> LDS bf16 ----
#pragma unroll
    for (int nt = 0; nt < 4; nt++) {
        int dim = nt * 16 + l15;
        float bb = g_fb2v[dim];
#pragma unroll
        for (int mt = 0; mt < 4; mt++) {
#pragma unroll
            for (int r = 0; r < 4; r++) {
                int edge = w * 64 + mt * 16 + quad * 4 + r;
                float v = fmaxf(acc[mt][nt][r] + bb, 0.f);
                sA[edge * 72 + dim] = (unsigned short)bf16rne(v);
            }
        }
    }
    __syncthreads();

    // ---- phase 3b: segmented run-max, lane = dim ----
    {
        const int ls0 = w * 64;
        const int gs0 = slot0 + ls0;
        int cur = -1;
        float vmax = 0.f;
        for (int s = ls0; s < ls0 + 64; s++) {
            int cj = scol[s];
            float v = b2f(sA[s * 72 + lane]);
            if (cj != cur) {
                if (cur >= 0) {
                    int lo = g_offs[cur], hi = g_offs[cur + 1];
                    if (lo >= gs0 && hi <= gs0 + 64)
                        g_agg[(size_t)cur * D_H + lane] = vmax;
                    else
                        atomicMax((unsigned*)&g_agg[(size_t)cur * D_H + lane], __float_as_uint(vmax));
                }
                cur = cj; vmax = v;
            } else {
                vmax = fmaxf(vmax, v);
            }
        }
        if (cur >= 0) {
            int lo = g_offs[cur], hi = g_offs[cur + 1];
            if (lo >= gs0 && hi <= gs0 + 64)
                g_agg[(size_t)cur * D_H + lane] = vmax;
            else
                atomicMax((unsigned*)&g_agg[(size_t)cur * D_H + lane], __float_as_uint(vmax));
        }
    }
}

// ---------------------------------------------------------------------------
// outmisc: blocks 0..2047 = out (relu(agg @ gW + gb)); 2048.. = pos/batch copy
// ---------------------------------------------------------------------------
__global__ __launch_bounds__(256) void outmisc_kernel(const void* __restrict__ x,
                                                      const void* __restrict__ gW,
                                                      const void* __restrict__ gb,
                                                      const int* __restrict__ batch,
                                                      const void* __restrict__ pos,
                                                      void* __restrict__ out) {
    const int bf = wave_probe(x);
    const int b = blockIdx.x;
    if (b < 2048) {
        int t = threadIdx.x, d = t & 127, half = t >> 7;
        float gcol[D_H];
#pragma unroll
        for (int k = 0; k < D_H; k++) gcol[k] = ldf(gW, k * D_OUT + d, bf);
        float bb = ldf(gb, d, bf);
        int n0 = b * 16 + half * 8;
        for (int r = 0; r < 8; r++) {
            int n = n0 + r;
            float acc = bb;
#pragma unroll
            for (int k = 0; k < D_H; k++) acc += g_agg[(size_t)n * D_H + k] * gcol[k];
            stf(out, n * D_OUT + d, fmaxf(acc, 0.f), bf);
        }
    } else {
        int i = (b - 2048) * 256 + threadIdx.x;
        if (bf) {
            if (i < NTOT * 3) ((unsigned short*)out)[OUT1_OFF + i] = ((const unsigned short*)pos)[i];
            if (i < NTOT)     ((unsigned short*)out)[OUT2_OFF + i] = (unsigned short)bf16rne((float)batch[i]);
        } else {
            if (i < NTOT * 3) ((float*)out)[OUT1_OFF + i] = ((const float*)pos)[i];
            if (i < NTOT)     ((float*)out)[OUT2_OFF + i] = (float)batch[i];
        }
    }
}

// ---------------------------------------------------------------------------
extern "C" void kernel_launch(void* const* d_in, const int* in_sizes, int n_in,
                              void* d_out, int out_size, void* d_ws, size_t ws_size,
                              hipStream_t stream) {
    const void* x     = d_in[0];
    const void* pos   = d_in[1];
    const int*  batch = (const int*)d_in[2];
    const void* fW1   = d_in[3];
    const void* fb1   = d_in[4];
    const void* fW2   = d_in[5];
    const void* fb2   = d_in[6];
    const void* gW    = d_in[7];
    const void* gb    = d_in[8];

    hipLaunchKernelGGL(prep_kernel,    dim3(2049),        dim3(256), 0, stream, x, pos, fW1, fb1, fW2, fb2);
    hipLaunchKernelGGL(knn_kernel,     dim3(NTOT / 64),   dim3(512), 0, stream);
    hipLaunchKernelGGL(scanA_kernel,   dim3(NTOT / 256),  dim3(256), 0, stream);
    hipLaunchKernelGGL(scanC_kernel,   dim3(NTOT / 256),  dim3(256), 0, stream);
    hipLaunchKernelGGL(scatter_kernel, dim3(E_TOT / 256), dim3(256), 0, stream);
    hipLaunchKernelGGL(edge_kernel,    dim3(E_TOT / 256), dim3(256), 0, stream);
    hipLaunchKernelGGL(outmisc_kernel, dim3(2048 + (NTOT * 3 + 255) / 256), dim3(256), 0, stream,
                       x, gW, gb, batch, pos, d_out);
}

// Round 2
// 270.611 us; speedup vs baseline: 1.0054x; 1.0054x over previous
//
#include <hip/hip_runtime.h>
#include <hip/hip_bf16.h>

// Problem constants (fixed by reference)
#define N_PER    4096
#define KNBR     16
#define NTOT     32768
#define D_IN     32
#define D_H      64
#define D_OUT    128
#define E_TOT    (NTOT * KNBR)            // 524288

#define OUT1_OFF (NTOT * D_OUT)           // pos output offset (elements)
#define OUT2_OFF (NTOT * D_OUT + NTOT*3)  // batch output offset (elements)

#define KNN_INF    3.4e38f
#define KNN_MARGIN 4e-3f   // covers |d'_mfma - d_exact| (<~9e-4 worst case) x2

typedef __attribute__((ext_vector_type(8)))  short bf16x8;   // MFMA A/B frag
typedef __attribute__((ext_vector_type(4)))  float f32x4;    // MFMA C/D frag (16x16)
typedef __attribute__((ext_vector_type(16))) float f32x16;   // MFMA C/D frag (32x32)

// ---------------------------------------------------------------------------
// Static device scratch; every buffer fully (re)written each call.
// ---------------------------------------------------------------------------
__device__ float          g_posf[NTOT * 3];       // f32 pos (exact bf16 upconvert)
__device__ float          g_scf[NTOT];            // per-node |p|^2 (unfused, = numpy sq)
__device__ __attribute__((aligned(16))) unsigned short g_knnA[NTOT * 16]; // per-node MFMA A frag (query side)
__device__ __attribute__((aligned(16))) unsigned short g_knnB[NTOT * 16]; // per-node MFMA B frag (candidate side)
__device__ int            g_nbr[E_TOT];
__device__ unsigned short g_base1h[NTOT * D_H];   // bf16 base1
__device__ uint4          g_Bfrag[2 * 4 * 64];    // W2 B-fragments [ks][nt][lane]
__device__ float          g_Wd[3 * D_H];
__device__ float          g_fb2v[D_H];
__device__ int            g_cnt[NTOT];
__device__ int            g_bsum[NTOT / 256];     // per-block cnt sums (scan)
__device__ int            g_offs[NTOT + 1];
__device__ int            g_cursor[NTOT];
__device__ int            g_inlist[E_TOT];
__device__ float          g_agg[NTOT * D_H];      // zero-inited (atomicMax targets)

__device__ __forceinline__ float ldf(const void* p, int i, int bf) {
    if (bf) return __uint_as_float(((unsigned)((const unsigned short*)p)[i]) << 16);
    return ((const float*)p)[i];
}
__device__ __forceinline__ unsigned bf16rne(float f) {
    unsigned u = __float_as_uint(f);
    return (u + 0x7FFFu + ((u >> 16) & 1u)) >> 16;
}
__device__ __forceinline__ void stf(void* p, int i, float v, int bf) {
    if (bf) ((unsigned short*)p)[i] = (unsigned short)bf16rne(v);
    else    ((float*)p)[i] = v;
}
__device__ __forceinline__ float b2f(unsigned short h) {
    return __uint_as_float(((unsigned)h) << 16);
}
// Inline dtype probe: majority vote over 64 words of a float tensor.
__device__ __forceinline__ int wave_probe(const void* x) {
    unsigned wv = ((const unsigned*)x)[threadIdx.x & 63];
    unsigned e = (wv >> 7) & 0xFFu;
    unsigned long long mk = __ballot(e >= 110u && e <= 140u);
    return (__popcll(mk) >= 32) ? 1 : 0;
}

// ---------------------------------------------------------------------------
// prep: blocks 0..1023    = pos->f32, |p|^2, knn MFMA frags, zero cnt/agg
//       blocks 1024..2047 = base1[n][d] (vectorized dual-dtype x loads)
//       block  2048       = stage edge-kernel weights (Wd, fb2, W2 B-frags)
// ---------------------------------------------------------------------------
__global__ __launch_bounds__(256) void prep_kernel(const void* __restrict__ x,
                                                   const void* __restrict__ pos,
                                                   const void* __restrict__ fW1,
                                                   const void* __restrict__ fb1,
                                                   const void* __restrict__ fW2,
                                                   const void* __restrict__ fb2) {
    const int bf = wave_probe(x);
    const int b = blockIdx.x;
    if (b < 1024) {
        const int i0 = b * 256 + threadIdx.x;
        const int stride = 1024 * 256;
        for (int i = i0; i < NTOT * 3; i += stride) g_posf[i] = ldf(pos, i, bf);
        {
#pragma clang fp contract(off)
            for (int i = i0; i < NTOT; i += stride) {
                float a  = ldf(pos, i * 3 + 0, bf);
                float c2 = ldf(pos, i * 3 + 1, bf);
                float c3 = ldf(pos, i * 3 + 2, bf);
                float sc = a * a + c2 * c2 + c3 * c3;
                g_scf[i] = sc;
                g_cnt[i] = 0;
                // hi/lo bf16 split of coords and |p|^2 for the MFMA distance scan.
                // K layout (16 slots, 11 used):
                //   A = [-2hx,-2hy,-2hz, -2lx,-2ly,-2lz, -2hx,-2hy,-2hz, 1, 1, 0..]
                //   B = [ hx,  hy,  hz,   hx,  hy,  hz,   lx,  ly,  lz, sch,scl,0..]
                // sum(A*B) = sc' - 2(h.h' + l.h' + h.l')  ~= sc' - 2 p.p'
                unsigned hx = bf16rne(a),  hy = bf16rne(c2), hz = bf16rne(c3);
                float fhx = b2f(hx), fhy = b2f(hy), fhz = b2f(hz);
                unsigned lx = bf16rne(a - fhx), ly = bf16rne(c2 - fhy), lz = bf16rne(c3 - fhz);
                unsigned sch = bf16rne(sc);
                unsigned scl = bf16rne(sc - b2f(sch));
                unsigned nx = bf16rne(-2.0f * fhx), ny = bf16rne(-2.0f * fhy), nz = bf16rne(-2.0f * fhz);
                unsigned ox = bf16rne(-2.0f * b2f(lx)), oy = bf16rne(-2.0f * b2f(ly)), oz = bf16rne(-2.0f * b2f(lz));
                const unsigned ONEB = 0x3F80u;
                uint4 A0 = make_uint4(nx | (ny << 16), nz | (ox << 16), oy | (oz << 16), nx | (ny << 16));
                uint4 A1 = make_uint4(nz | (ONEB << 16), ONEB, 0u, 0u);
                uint4 B0 = make_uint4(hx | (hy << 16), hz | (hx << 16), hy | (hz << 16), lx | (ly << 16));
                uint4 B1 = make_uint4(lz | (sch << 16), scl, 0u, 0u);
                *(uint4*)&g_knnA[(size_t)i * 16]     = A0;
                *(uint4*)&g_knnA[(size_t)i * 16 + 8] = A1;
                *(uint4*)&g_knnB[(size_t)i * 16]     = B0;
                *(uint4*)&g_knnB[(size_t)i * 16 + 8] = B1;
            }
        }
        for (int i = i0; i < NTOT * D_H; i += stride) g_agg[i] = 0.0f;
    } else if (b < 2048) {
        int lane = threadIdx.x & 63, wid = threadIdx.x >> 6;
        int n0 = (b - 1024) * 32 + wid * 8;
        float wcol[D_IN];
#pragma unroll
        for (int k = 0; k < D_IN; k++) wcol[k] = ldf(fW1, k * D_H + lane, bf);
        float bb = ldf(fb1, lane, bf);
        if (bf) {
            const unsigned short* xp = (const unsigned short*)x;
            for (int r = 0; r < 8; r++) {
                int n = n0 + r;
                const uint4* xr = (const uint4*)(xp + (size_t)n * D_IN);  // 32 bf16 = 4x uint4
                float acc = bb;
#pragma unroll
                for (int q4 = 0; q4 < 4; q4++) {
                    uint4 w4 = xr[q4];
                    unsigned ww[4] = {w4.x, w4.y, w4.z, w4.w};
#pragma unroll
                    for (int p = 0; p < 4; p++) {
                        int k = q4 * 8 + p * 2;
                        acc += __uint_as_float(ww[p] << 16) * wcol[k];
                        acc += __uint_as_float(ww[p] & 0xFFFF0000u) * wcol[k + 1];
                    }
                }
                g_base1h[(size_t)n * D_H + lane] = (unsigned short)bf16rne(acc);
            }
        } else {
            const float* xp = (const float*)x;
            for (int r = 0; r < 8; r++) {
                int n = n0 + r;
                const float4* xr = (const float4*)(xp + (size_t)n * D_IN);
                float acc = bb;
#pragma unroll
                for (int q4 = 0; q4 < 8; q4++) {
                    float4 w4 = xr[q4];
                    int k = q4 * 4;
                    acc += w4.x * wcol[k] + w4.y * wcol[k + 1] + w4.z * wcol[k + 2] + w4.w * wcol[k + 3];
                }
                g_base1h[(size_t)n * D_H + lane] = (unsigned short)bf16rne(acc);
            }
        }
    } else {
        for (int t = threadIdx.x; t < 3 * D_H; t += 256) g_Wd[t] = ldf(fW1, D_IN * D_H + t, bf);
        if (threadIdx.x < D_H) g_fb2v[threadIdx.x] = ldf(fb2, threadIdx.x, bf);
        for (int idx = threadIdx.x; idx < 512; idx += 256) {
            int lane = idx & 63, nt = (idx >> 6) & 3, ks = idx >> 8;
            int n = nt * 16 + (lane & 15);
            int k0 = ks * 32 + ((lane >> 4) << 3);
            unsigned wds[4];
#pragma unroll
            for (int jp = 0; jp < 4; jp++) {
                unsigned lo = bf16rne(ldf(fW2, (k0 + 2 * jp) * D_H + n, bf));
                unsigned hi = bf16rne(ldf(fW2, (k0 + 2 * jp + 1) * D_H + n, bf));
                wds[jp] = lo | (hi << 16);
            }
            g_Bfrag[idx] = make_uint4(wds[0], wds[1], wds[2], wds[3]);
        }
    }
}

// ---------------------------------------------------------------------------
// 64-lane bitonic helpers (identical networks to the previously-passing kernel)
// ---------------------------------------------------------------------------
__device__ __forceinline__ void knn_sortval(float& v, int lane) {
#pragma unroll
    for (int k = 2; k <= 64; k <<= 1) {
#pragma unroll
        for (int j2 = k >> 1; j2 >= 1; j2 >>= 1) {
            float pv = __shfl_xor(v, j2);
            bool keepMin = (((lane & j2) == 0) == ((lane & k) == 0));
            bool tp = ((pv < v) == keepMin);
            v = tp ? pv : v;
        }
    }
}
__device__ __forceinline__ void knn_sortpair(float& d, int& idx, int lane) {
#pragma unroll
    for (int k = 2; k <= 64; k <<= 1) {
#pragma unroll
        for (int j2 = k >> 1; j2 >= 1; j2 >>= 1) {
            float pd = __shfl_xor(d, j2);
            int   pi = __shfl_xor(idx, j2);
            bool keepMin = (((lane & j2) == 0) == ((lane & k) == 0));
            bool lt = (pd < d) || (pd == d && pi < idx);
            bool tp = (lt == keepMin);
            d   = tp ? pd : d;
            idx = tp ? pi : idx;
        }
    }
}

// ---------------------------------------------------------------------------
// KNN via MFMA distance tiles. 1024 blocks x 512 threads = 8 waves / block.
// Block owns 32 queries (one 32-row M-tile); wave w owns a 512-candidate
// slice (16 MFMA 32x32x16 tiles per scan).
// d' = sc_j - 2 p_i.p_j on hi/lo-split bf16 frags (err <~9e-4 < KNN_MARGIN).
// scan1: per-(row, col-class, slice) mins (256 disjoint 16-cand partitions,
//        folded x4 -> 64 disjoint 64-cand unions) -> T'[q] = 16th-smallest
//        union-min + margin (>= true d_16 => >=16 survivors, top-16 kept).
// scan2: identical MFMA recompute; survivor compaction = per-lane LDS
//        atomicAdd (all-false fast path: v_cmp + execz skip).
// final: exact unfused f32 d + (d, idx) bitonic top-16 (selection identical
//        to previous kernel); exact slow path if > 64 survivors.
// ---------------------------------------------------------------------------
__global__ __launch_bounds__(512) void knn_kernel() {
#pragma clang fp contract(off)
    __shared__ float          s_min[32][256];
    __shared__ float          s_T[32];
    __shared__ int            s_cnt[32];
    __shared__ unsigned short s_list[32][64];

    const int t     = threadIdx.x;
    const int lane  = t & 63;
    const int w     = t >> 6;          // candidate slice 0..7
    const int half  = lane >> 5;
    const int col   = lane & 31;
    const int qbase = blockIdx.x * 32;
    const int cbase = (qbase >> 12) << 12;

    if (t < 32) s_cnt[t] = 0;

    // A-frag: query row = col, k-half = half
    const int qrow = qbase + col;
    const bf16x8 afrag = *(const bf16x8*)&g_knnA[(size_t)qrow * 16 + half * 8];
    // B-frag base for this lane's candidate column; +512 ushorts per 32-cand tile
    const unsigned short* bp = g_knnB + (size_t)(cbase + w * 512 + col) * 16 + half * 8;

    const f32x16 z = {};

    // ---- scan 1: min d' per (query row, col-class) within this slice ----
    float m[16];
#pragma unroll
    for (int i = 0; i < 16; i++) m[i] = KNN_INF;
    {
        bf16x8 nb0 = *(const bf16x8*)(bp + 0 * 512);
        bf16x8 nb1 = *(const bf16x8*)(bp + 1 * 512);
        bf16x8 nb2 = *(const bf16x8*)(bp + 2 * 512);
        bf16x8 nb3 = *(const bf16x8*)(bp + 3 * 512);
        for (int g = 0; g < 4; g++) {
            bf16x8 cb0 = nb0, cb1 = nb1, cb2 = nb2, cb3 = nb3;
            if (g < 3) {
                const unsigned short* np = bp + (g + 1) * 2048;
                nb0 = *(const bf16x8*)(np + 0 * 512);
                nb1 = *(const bf16x8*)(np + 1 * 512);
                nb2 = *(const bf16x8*)(np + 2 * 512);
                nb3 = *(const bf16x8*)(np + 3 * 512);
            }
            f32x16 c0 = __builtin_amdgcn_mfma_f32_32x32x16_bf16(afrag, cb0, z, 0, 0, 0);
            f32x16 c1 = __builtin_amdgcn_mfma_f32_32x32x16_bf16(afrag, cb1, z, 0, 0, 0);
            f32x16 c2 = __builtin_amdgcn_mfma_f32_32x32x16_bf16(afrag, cb2, z, 0, 0, 0);
            f32x16 c3 = __builtin_amdgcn_mfma_f32_32x32x16_bf16(afrag, cb3, z, 0, 0, 0);
#pragma unroll
            for (int i = 0; i < 16; i++)
                m[i] = fminf(fminf(fminf(c0[i], c1[i]), c2[i]), fminf(c3[i], m[i]));
        }
    }
    // C layout (32x32): col = lane&31, row = (reg&3) + 8*(reg>>2) + 4*(lane>>5)
#pragma unroll
    for (int i = 0; i < 16; i++) {
        int row = (i & 3) + 8 * (i >> 2) + 4 * half;
        s_min[row][w * 32 + col] = m[i];
    }
    __syncthreads();

    // ---- threshold: T'[q] = 16th smallest of 64 disjoint union-mins + margin ----
    for (int it = 0; it < 4; it++) {
        int q = w * 4 + it;
        float v = fminf(fminf(s_min[q][lane], s_min[q][64 + lane]),
                        fminf(s_min[q][128 + lane], s_min[q][192 + lane]));
        knn_sortval(v, lane);
        if (lane == 15) s_T[q] = v + KNN_MARGIN;
    }
    __syncthreads();

    // ---- scan 2: identical MFMA recompute, per-lane atomic compaction ----
    float Treg[16];
#pragma unroll
    for (int i = 0; i < 16; i++) {
        int row = (i & 3) + 8 * (i >> 2) + 4 * half;
        Treg[i] = s_T[row];
    }
    {
        bf16x8 nb0 = *(const bf16x8*)(bp + 0 * 512);
        bf16x8 nb1 = *(const bf16x8*)(bp + 1 * 512);
        bf16x8 nb2 = *(const bf16x8*)(bp + 2 * 512);
        bf16x8 nb3 = *(const bf16x8*)(bp + 3 * 512);
        for (int g = 0; g < 4; g++) {
            bf16x8 cb[4] = {nb0, nb1, nb2, nb3};
            if (g < 3) {
                const unsigned short* np = bp + (g + 1) * 2048;
                nb0 = *(const bf16x8*)(np + 0 * 512);
                nb1 = *(const bf16x8*)(np + 1 * 512);
                nb2 = *(const bf16x8*)(np + 2 * 512);
                nb3 = *(const bf16x8*)(np + 3 * 512);
            }
#pragma unroll
            for (int u = 0; u < 4; u++) {
                f32x16 c = __builtin_amdgcn_mfma_f32_32x32x16_bf16(afrag, cb[u], z, 0, 0, 0);
                int lc = w * 512 + (g * 4 + u) * 32 + col;
#pragma unroll
                for (int i = 0; i < 16; i++) {
                    if (c[i] <= Treg[i]) {
                        int q = (i & 3) + 8 * (i >> 2) + 4 * half;
                        int slot = atomicAdd(&s_cnt[q], 1);
                        if (slot < 64) s_list[q][slot] = (unsigned short)lc;
                    }
                }
            }
        }
    }
    __syncthreads();

    // ---- final: exact unfused d for survivors, (d, idx) bitonic top-16 ----
    for (int it = 0; it < 4; it++) {
        int ql = w * 4 + it;
        int q  = qbase + ql;
        float qx = g_posf[q * 3 + 0], qy = g_posf[q * 3 + 1], qz = g_posf[q * 3 + 2];
        float qs = g_scf[q];
        int S = s_cnt[ql];
        if (S <= 64) {
            int idx = 0x7FFFFFFF;
            float d = KNN_INF;
            if (lane < S) {
                idx = cbase + (int)s_list[ql][lane];
                float px = g_posf[idx * 3], py = g_posf[idx * 3 + 1], pz = g_posf[idx * 3 + 2];
                float sc = g_scf[idx];
                float dot = px * qx + py * qy + pz * qz;
                d = (qs + sc) - 2.0f * dot;
            }
            knn_sortpair(d, idx, lane);
            if (lane < 16) {
                g_nbr[q * KNBR + lane] = idx;
                atomicAdd(&g_cnt[idx & (NTOT - 1)], 1);
            }
        } else {
            // exact slow path: 16 sequential argmin passes over graph's pos
            const float* cp  = g_posf + cbase * 3;
            const float* csc = g_scf + cbase;
            float lastd = -KNN_INF; int lasti = -1;
            for (int t16 = 0; t16 < 16; t16++) {
                float bd = KNN_INF; int bi = 0x7FFFFFFF;
                for (int cc = 0; cc < 64; cc++) {
                    int jj = cc * 64 + lane;
                    float px = cp[jj * 3], py = cp[jj * 3 + 1], pz = cp[jj * 3 + 2];
                    float sc = csc[jj];
                    float dot = px * qx + py * qy + pz * qz;
                    float dd = (qs + sc) - 2.0f * dot;
                    int gj = cbase + jj;
                    bool after  = (dd > lastd) || (dd == lastd && gj > lasti);
                    bool better = (dd < bd) || (dd == bd && gj < bi);
                    if (after && better) { bd = dd; bi = gj; }
                }
#pragma unroll
                for (int s2 = 1; s2 < 64; s2 <<= 1) {
                    float od = __shfl_xor(bd, s2);
                    int   oi = __shfl_xor(bi, s2);
                    if (od < bd || (od == bd && oi < bi)) { bd = od; bi = oi; }
                }
                if (lane == 0) {
                    g_nbr[q * KNBR + t16] = bi;
                    atomicAdd(&g_cnt[bi & (NTOT - 1)], 1);
                }
                lastd = bd; lasti = bi;
            }
        }
    }
}

// ---------------------------------------------------------------------------
// scanA: per-256-block sums of g_cnt
// ---------------------------------------------------------------------------
__global__ __launch_bounds__(256) void scanA_kernel() {
    __shared__ int red[4];
    int t = threadIdx.x, lane = t & 63, w = t >> 6;
    int v = g_cnt[blockIdx.x * 256 + t];
    int s = v;
#pragma unroll
    for (int off = 1; off < 64; off <<= 1) s += __shfl_xor(s, off);
    if (lane == 0) red[w] = s;
    __syncthreads();
    if (t == 0) g_bsum[blockIdx.x] = red[0] + red[1] + red[2] + red[3];
}

// ---------------------------------------------------------------------------
// scanC: each block redundantly sums its prior block-sums, then local scan.
// ---------------------------------------------------------------------------
__global__ __launch_bounds__(256) void scanC_kernel() {
    __shared__ int sred[4];
    __shared__ int wsum[4];
    int t = threadIdx.x, lane = t & 63, w = t >> 6;
    int contrib = (t < 128 && t < blockIdx.x) ? g_bsum[t] : 0;
    int rs = contrib;
#pragma unroll
    for (int off = 1; off < 64; off <<= 1) rs += __shfl_xor(rs, off);
    if (lane == 0) sred[w] = rs;
    __syncthreads();
    int base = sred[0] + sred[1] + sred[2] + sred[3];

    int i = blockIdx.x * 256 + t;
    int v = g_cnt[i];
    int inc = v;
#pragma unroll
    for (int off = 1; off < 64; off <<= 1) {
        int u = __shfl_up(inc, off);
        if (lane >= off) inc += u;
    }
    if (lane == 63) wsum[w] = inc;
    __syncthreads();
    int wbase = 0;
    for (int k = 0; k < w; k++) wbase += wsum[k];
    int excl = base + wbase + inc - v;
    g_offs[i] = excl;
    g_cursor[i] = excl;
    if (i == NTOT - 1) g_offs[NTOT] = E_TOT;
}

__global__ void scatter_kernel() {
    int e = blockIdx.x * 256 + threadIdx.x;
    int c = g_nbr[e] & (NTOT - 1);
    int slot = atomicAdd(&g_cursor[c], 1);
    g_inlist[slot & (E_TOT - 1)] = e;
}

// ---------------------------------------------------------------------------
// Edge kernel (MFMA): unchanged.
// ---------------------------------------------------------------------------
__global__ __launch_bounds__(256) void edge_kernel() {
    __shared__ unsigned short sA[256 * 72];
    __shared__ int scol[256];
    const int t    = threadIdx.x;
    const int lane = t & 63;
    const int w    = t >> 6;
    const int slot0 = blockIdx.x * 256;

    // ---- phase 1: h1 for this thread's edge ----
    {
        int e = g_inlist[slot0 + t];
        int n = (e >> 4) & (NTOT - 1);
        int j = g_nbr[e] & (NTOT - 1);
        scol[t] = j;
        float dx = g_posf[n * 3 + 0] - g_posf[j * 3 + 0];
        float dy = g_posf[n * 3 + 1] - g_posf[j * 3 + 1];
        float dz = g_posf[n * 3 + 2] - g_posf[j * 3 + 2];
        const unsigned short* b1 = g_base1h + (size_t)n * D_H;
#pragma unroll
        for (int d0 = 0; d0 < D_H; d0 += 8) {
            uint4 p = *(const uint4*)(b1 + d0);
            unsigned pw[4] = {p.x, p.y, p.z, p.w};
            unsigned qw[4];
#pragma unroll
            for (int jp = 0; jp < 4; jp++) {
                int d = d0 + 2 * jp;
                float v0 = __uint_as_float(pw[jp] << 16)
                         + dx * g_Wd[d]     + dy * g_Wd[64 + d]     + dz * g_Wd[128 + d];
                float v1 = __uint_as_float(pw[jp] & 0xFFFF0000u)
                         + dx * g_Wd[d + 1] + dy * g_Wd[64 + d + 1] + dz * g_Wd[128 + d + 1];
                v0 = fmaxf(v0, 0.f); v1 = fmaxf(v1, 0.f);
                qw[jp] = bf16rne(v0) | (bf16rne(v1) << 16);
            }
            *(uint4*)(&sA[t * 72 + d0]) = make_uint4(qw[0], qw[1], qw[2], qw[3]);
        }
    }
    __syncthreads();

    // ---- phase 2: MFMA h2 = h1 @ W2 ----
    f32x4 acc[4][4];
#pragma unroll
    for (int a = 0; a < 4; a++)
#pragma unroll
        for (int b = 0; b < 4; b++) acc[a][b] = (f32x4){0.f, 0.f, 0.f, 0.f};

    const int quad = lane >> 4;
    const int l15  = lane & 15;
#pragma unroll
    for (int ks = 0; ks < 2; ks++) {
        bf16x8 bfrag[4];
#pragma unroll
        for (int nt = 0; nt < 4; nt++)
            bfrag[nt] = ((const bf16x8*)g_Bfrag)[ks * 256 + nt * 64 + lane];
#pragma unroll
        for (int mt = 0; mt < 4; mt++) {
            int row = w * 64 + mt * 16 + l15;
            bf16x8 afrag = *(const bf16x8*)(&sA[row * 72 + ks * 32 + quad * 8]);
#pragma unroll
            for (int nt = 0; nt < 4; nt++)
                acc[mt][nt] = __builtin_amdgcn_mfma_f32_16x16x32_bf16(afrag, bfrag[nt], acc[mt][nt], 0, 0, 0);
        }
    }
    __syncthreads();

    // ---- phase 3a: relu(h2 + b2) -> LDS bf16 ----
#pragma unroll
    for (int nt = 0; nt < 4; nt++) {
        int dim = nt * 16 + l15;
        float bb = g_fb2v[dim];
#pragma unroll
        for (int mt = 0; mt < 4; mt++) {
#pragma unroll
            for (int r = 0; r < 4; r++) {
                int edge = w * 64 + mt * 16 + quad * 4 + r;
                float v = fmaxf(acc[mt][nt][r] + bb, 0.f);
                sA[edge * 72 + dim] = (unsigned short)bf16rne(v);
            }
        }
    }
    __syncthreads();

    // ---- phase 3b: segmented run-max, lane = dim ----
    {
        const int ls0 = w * 64;
        const int gs0 = slot0 + ls0;
        int cur = -1;
        float vmax = 0.f;
        for (int s = ls0; s < ls0 + 64; s++) {
            int cj = scol[s];
            float v = b2f(sA[s * 72 + lane]);
            if (cj != cur) {
                if (cur >= 0) {
                    int lo = g_offs[cur], hi = g_offs[cur + 1];
                    if (lo >= gs0 && hi <= gs0 + 64)
                        g_agg[(size_t)cur * D_H + lane] = vmax;
                    else
                        atomicMax((unsigned*)&g_agg[(size_t)cur * D_H + lane], __float_as_uint(vmax));
                }
                cur = cj; vmax = v;
            } else {
                vmax = fmaxf(vmax, v);
            }
        }
        if (cur >= 0) {
            int lo = g_offs[cur], hi = g_offs[cur + 1];
            if (lo >= gs0 && hi <= gs0 + 64)
                g_agg[(size_t)cur * D_H + lane] = vmax;
            else
                atomicMax((unsigned*)&g_agg[(size_t)cur * D_H + lane], __float_as_uint(vmax));
        }
    }
}

// ---------------------------------------------------------------------------
// outmisc: blocks 0..2047 = out (relu(agg @ gW + gb)); 2048.. = pos/batch copy
// ---------------------------------------------------------------------------
__global__ __launch_bounds__(256) void outmisc_kernel(const void* __restrict__ x,
                                                      const void* __restrict__ gW,
                                                      const void* __restrict__ gb,
                                                      const int* __restrict__ batch,
                                                      const void* __restrict__ pos,
                                                      void* __restrict__ out) {
    const int bf = wave_probe(x);
    const int b = blockIdx.x;
    if (b < 2048) {
        int t = threadIdx.x, d = t & 127, half = t >> 7;
        float gcol[D_H];
#pragma unroll
        for (int k = 0; k < D_H; k++) gcol[k] = ldf(gW, k * D_OUT + d, bf);
        float bb = ldf(gb, d, bf);
        int n0 = b * 16 + half * 8;
        for (int r = 0; r < 8; r++) {
            int n = n0 + r;
            float acc = bb;
#pragma unroll
            for (int k = 0; k < D_H; k++) acc += g_agg[(size_t)n * D_H + k] * gcol[k];
            stf(out, n * D_OUT + d, fmaxf(acc, 0.f), bf);
        }
    } else {
        int i = (b - 2048) * 256 + threadIdx.x;
        if (bf) {
            if (i < NTOT * 3) ((unsigned short*)out)[OUT1_OFF + i] = ((const unsigned short*)pos)[i];
            if (i < NTOT)     ((unsigned short*)out)[OUT2_OFF + i] = (unsigned short)bf16rne((float)batch[i]);
        } else {
            if (i < NTOT * 3) ((float*)out)[OUT1_OFF + i] = ((const float*)pos)[i];
            if (i < NTOT)     ((float*)out)[OUT2_OFF + i] = (float)batch[i];
        }
    }
}

// ---------------------------------------------------------------------------
extern "C" void kernel_launch(void* const* d_in, const int* in_sizes, int n_in,
                              void* d_out, int out_size, void* d_ws, size_t ws_size,
                              hipStream_t stream) {
    const void* x     = d_in[0];
    const void* pos   = d_in[1];
    const int*  batch = (const int*)d_in[2];
    const void* fW1   = d_in[3];
    const void* fb1   = d_in[4];
    const void* fW2   = d_in[5];
    const void* fb2   = d_in[6];
    const void* gW    = d_in[7];
    const void* gb    = d_in[8];

    hipLaunchKernelGGL(prep_kernel,    dim3(2049),        dim3(256), 0, stream, x, pos, fW1, fb1, fW2, fb2);
    hipLaunchKernelGGL(knn_kernel,     dim3(NTOT / 32),   dim3(512), 0, stream);
    hipLaunchKernelGGL(scanA_kernel,   dim3(NTOT / 256),  dim3(256), 0, stream);
    hipLaunchKernelGGL(scanC_kernel,   dim3(NTOT / 256),  dim3(256), 0, stream);
    hipLaunchKernelGGL(scatter_kernel, dim3(E_TOT / 256), dim3(256), 0, stream);
    hipLaunchKernelGGL(edge_kernel,    dim3(E_TOT / 256), dim3(256), 0, stream);
    hipLaunchKernelGGL(outmisc_kernel, dim3(2048 + (NTOT * 3 + 255) / 256), dim3(256), 0, stream,
                       x, gW, gb, batch, pos, d_out);
}